// Round 7
// baseline (89.100 us; speedup 1.0000x reference)
//
#include <hip/hip_runtime.h>

// DiversityLoss: reference collapses to
//   out = (||colsum||^2 - B * sum(x^2)) / (D * B * (B-1))
// B=64, D=3*256*256=196608. Single memory-bound pass over 50.3 MB fp32.
//
// Round 7: MEASUREMENT PROBE. Six rounds of structural variation (occupancy
// 3->32 waves/CU, 1->4 KB bursts, column-parked vs row-front order, nt,
// fusion) all landed at 79.2-80.5 us total: the main pass's true duration m
// has never been directly observed (always under the 41.8-us top-5 cutoff).
// Here div_main is dispatched TWICE (idempotent: second dispatch rewrites
// byte-identical partials, finalize unchanged -> correctness preserved).
// Delta vs 79.3 us baseline == m + one dispatch gap. Pre-committed read:
//   <=87  -> m small, kernels at floor, declare roofline.
//   90-100-> m ~ 10-20 us, one last finalize-removal attempt, then stop.
//   >=108 -> m ~ 30 us, streaming wall is real, attack cache-state next.

#define NBLK 256
#define NTHR 192   // NBLK * NTHR == D4 == 49152 float4 columns

__global__ __launch_bounds__(NTHR) void div_main(const float4* __restrict__ x4,
                                                 float* __restrict__ partial,
                                                 int D4) {
    const int col = blockIdx.x * NTHR + threadIdx.x;   // one f4-column per thread
    const float4* p = x4 + col;

    float4 acc = make_float4(0.f, 0.f, 0.f, 0.f);
    float sq = 0.f;

    #pragma unroll 16
    for (int r = 0; r < 64; ++r) {
        float4 v = p[(size_t)r * (size_t)D4];
        acc.x += v.x; acc.y += v.y; acc.z += v.z; acc.w += v.w;
        sq = fmaf(v.x, v.x, sq);
        sq = fmaf(v.y, v.y, sq);
        sq = fmaf(v.z, v.z, sq);
        sq = fmaf(v.w, v.w, sq);
    }

    // Thread holds the COMPLETE column sum for its 4 columns.
    float contrib = acc.x * acc.x + acc.y * acc.y + acc.z * acc.z + acc.w * acc.w
                  - 64.0f * sq;

    // Block reduction: wave-64 shuffle, then 3 wave results via LDS.
    #pragma unroll
    for (int off = 32; off > 0; off >>= 1)
        contrib += __shfl_down(contrib, off, 64);

    __shared__ float wsum[3];
    const int wave = threadIdx.x >> 6;
    if ((threadIdx.x & 63) == 0) wsum[wave] = contrib;
    __syncthreads();
    if (threadIdx.x == 0)
        partial[blockIdx.x] = wsum[0] + wsum[1] + wsum[2];
}

__global__ __launch_bounds__(256) void div_finalize(const float* __restrict__ partial,
                                                    float* __restrict__ out,
                                                    float scale) {
    const int t = threadIdx.x;
    float v = partial[t];    // exactly NBLK == 256 partials

    #pragma unroll
    for (int off = 32; off > 0; off >>= 1)
        v += __shfl_down(v, off, 64);

    __shared__ float wsum[4];
    if ((t & 63) == 0) wsum[t >> 6] = v;
    __syncthreads();
    if (t == 0)
        out[0] = (wsum[0] + wsum[1] + wsum[2] + wsum[3]) * scale;
}

extern "C" void kernel_launch(void* const* d_in, const int* in_sizes, int n_in,
                              void* d_out, int out_size, void* d_ws, size_t ws_size,
                              hipStream_t stream) {
    const float* x = (const float*)d_in[0];
    float* out = (float*)d_out;
    float* partial = (float*)d_ws;

    const int B = 64;
    const int total = in_sizes[0];          // 12,582,912 elements
    const int D = total / B;                // 196,608
    const int D4 = D / 4;                   // 49,152

    const float scale = (float)(1.0 / ((double)D * (double)B * (double)(B - 1)));

    // PROBE: dispatch the main pass twice (idempotent). Delta in total vs
    // the 79.3-us baseline measures the main pass's true duration, which has
    // never been directly observable (below the rocprof top-5 cutoff).
    div_main<<<NBLK, NTHR, 0, stream>>>((const float4*)x, partial, D4);
    div_main<<<NBLK, NTHR, 0, stream>>>((const float4*)x, partial, D4);
    div_finalize<<<1, 256, 0, stream>>>(partial, out, scale);
}

// Round 8
// 82.896 us; speedup vs baseline: 1.0748x; 1.0748x over previous
//
#include <hip/hip_runtime.h>

// DiversityLoss: reference collapses to
//   out = (||colsum||^2 - B * sum(x^2)) / (D * B * (B-1))
// B=64, D=3*256*256=196608. Single memory-bound pass over 50.3 MB fp32.
//
// Round 8: probe (R7, doubled main) measured m = main-pass duration ~ 8 us
// = the 50.3 MB / 6.3 TB/s roofline exactly. The pass has been at the memory
// ceiling all along; remaining controllable cost is only the finalize
// dispatch. Replace it with a single hardware fp32 atomicAdd per block
// (256 total, no fences — the atomic carries the value, unlike R3's
// acq_rel ticket protocol that cost +14 us). out is zeroed by a 4-byte
// graph memset node. Budget: fill 42 (harness, fixed) + main 8 (roofline)
// + memset ~1.5 + gaps. Pre-committed: if absmax trips tolerance or dur
// does not improve, revert to R6 split form and declare roofline.

#define NBLK 256
#define NTHR 192   // NBLK * NTHR == D4 == 49152 float4 columns

__global__ __launch_bounds__(NTHR) void div_main(const float4* __restrict__ x4,
                                                 float* __restrict__ out,
                                                 int D4, float scale) {
    const int col = blockIdx.x * NTHR + threadIdx.x;   // one f4-column per thread
    const float4* p = x4 + col;

    float4 acc = make_float4(0.f, 0.f, 0.f, 0.f);
    float sq = 0.f;

    #pragma unroll 16
    for (int r = 0; r < 64; ++r) {
        float4 v = p[(size_t)r * (size_t)D4];
        acc.x += v.x; acc.y += v.y; acc.z += v.z; acc.w += v.w;
        sq = fmaf(v.x, v.x, sq);
        sq = fmaf(v.y, v.y, sq);
        sq = fmaf(v.z, v.z, sq);
        sq = fmaf(v.w, v.w, sq);
    }

    // Thread holds the COMPLETE column sum for its 4 columns.
    float contrib = acc.x * acc.x + acc.y * acc.y + acc.z * acc.z + acc.w * acc.w
                  - 64.0f * sq;

    // Block reduction: wave-64 shuffle, then 3 wave results via LDS.
    #pragma unroll
    for (int off = 32; off > 0; off >>= 1)
        contrib += __shfl_down(contrib, off, 64);

    __shared__ float wsum[3];
    const int wave = threadIdx.x >> 6;
    if ((threadIdx.x & 63) == 0) wsum[wave] = contrib;
    __syncthreads();
    if (threadIdx.x == 0)
        atomicAdd(out, (wsum[0] + wsum[1] + wsum[2]) * scale);
}

extern "C" void kernel_launch(void* const* d_in, const int* in_sizes, int n_in,
                              void* d_out, int out_size, void* d_ws, size_t ws_size,
                              hipStream_t stream) {
    const float* x = (const float*)d_in[0];
    float* out = (float*)d_out;

    const int B = 64;
    const int total = in_sizes[0];          // 12,582,912 elements
    const int D = total / B;                // 196,608
    const int D4 = D / 4;                   // 49,152

    const float scale = (float)(1.0 / ((double)D * (double)B * (double)(B - 1)));

    // Graph-capturable 4-byte memset node zeroes the accumulator each replay.
    (void)hipMemsetAsync(out, 0, sizeof(float), stream);
    div_main<<<NBLK, NTHR, 0, stream>>>((const float4*)x, out, D4, scale);
}

// Round 9
// 80.366 us; speedup vs baseline: 1.1087x; 1.0315x over previous
//
#include <hip/hip_runtime.h>

// DiversityLoss: reference collapses to
//   out = (||colsum||^2 - B * sum(x^2)) / (D * B * (B-1))
// B=64, D=3*256*256=196608. Single memory-bound pass over 50.3 MB fp32.
//
// FINAL (round 9 = revert to round-6 form, best measured: 79.2 us).
// The main pass was directly measured at ~8 us via a kernel-doubling probe
// (R7: +9.8 us for a second identical dispatch) == 50.3 MB / 6.3 TB/s
// achievable HBM BW -> AT THE MEMORY ROOFLINE. The remaining ~71 us of the
// benchmark total is harness-fixed cost (42 us workspace-poison fill at 80%
// of HBM peak, restore traffic, dispatch gaps). Fusion variants measured
// net-negative: acq_rel last-block ticket +23 us (768 release fences =
// L2 writeback storms on non-coherent per-XCD L2s); plain float atomicAdd
// + 4-byte memset node +3.7 us. Structural axes all verified flat at the
// ceiling: occupancy 3->32 waves/CU, DRAM burst 1->4 KB, column-parked vs
// contiguous row-front order, nontemporal hints (those regress: nt defeats
// cache residency), 192-49152-thread grids.
//
// Layout: one thread per float4-column (256 blocks x 192 thr = 49152 = D4);
// each thread walks all 64 rows of its column -> whole grid sweeps one
// contiguous 786 KB row-front per iteration; full column sum stays in one
// thread (no LDS combine, no cross-block traffic); unroll-16 keeps 16 loads
// in flight. Deterministic per-block partials + tiny finalize (no atomics).

#define NBLK 256
#define NTHR 192   // NBLK * NTHR == D4 == 49152 float4 columns

__global__ __launch_bounds__(NTHR) void div_main(const float4* __restrict__ x4,
                                                 float* __restrict__ partial,
                                                 int D4) {
    const int col = blockIdx.x * NTHR + threadIdx.x;   // one f4-column per thread
    const float4* p = x4 + col;

    float4 acc = make_float4(0.f, 0.f, 0.f, 0.f);
    float sq = 0.f;

    #pragma unroll 16
    for (int r = 0; r < 64; ++r) {
        float4 v = p[(size_t)r * (size_t)D4];
        acc.x += v.x; acc.y += v.y; acc.z += v.z; acc.w += v.w;
        sq = fmaf(v.x, v.x, sq);
        sq = fmaf(v.y, v.y, sq);
        sq = fmaf(v.z, v.z, sq);
        sq = fmaf(v.w, v.w, sq);
    }

    // Thread holds the COMPLETE column sum for its 4 columns.
    float contrib = acc.x * acc.x + acc.y * acc.y + acc.z * acc.z + acc.w * acc.w
                  - 64.0f * sq;

    // Block reduction: wave-64 shuffle, then 3 wave results via LDS.
    #pragma unroll
    for (int off = 32; off > 0; off >>= 1)
        contrib += __shfl_down(contrib, off, 64);

    __shared__ float wsum[3];
    const int wave = threadIdx.x >> 6;
    if ((threadIdx.x & 63) == 0) wsum[wave] = contrib;
    __syncthreads();
    if (threadIdx.x == 0)
        partial[blockIdx.x] = wsum[0] + wsum[1] + wsum[2];
}

__global__ __launch_bounds__(256) void div_finalize(const float* __restrict__ partial,
                                                    float* __restrict__ out,
                                                    float scale) {
    const int t = threadIdx.x;
    float v = partial[t];    // exactly NBLK == 256 partials

    #pragma unroll
    for (int off = 32; off > 0; off >>= 1)
        v += __shfl_down(v, off, 64);

    __shared__ float wsum[4];
    if ((t & 63) == 0) wsum[t >> 6] = v;
    __syncthreads();
    if (t == 0)
        out[0] = (wsum[0] + wsum[1] + wsum[2] + wsum[3]) * scale;
}

extern "C" void kernel_launch(void* const* d_in, const int* in_sizes, int n_in,
                              void* d_out, int out_size, void* d_ws, size_t ws_size,
                              hipStream_t stream) {
    const float* x = (const float*)d_in[0];
    float* out = (float*)d_out;
    float* partial = (float*)d_ws;

    const int B = 64;
    const int total = in_sizes[0];          // 12,582,912 elements
    const int D = total / B;                // 196,608
    const int D4 = D / 4;                   // 49,152

    const float scale = (float)(1.0 / ((double)D * (double)B * (double)(B - 1)));

    div_main<<<NBLK, NTHR, 0, stream>>>((const float4*)x, partial, D4);
    div_finalize<<<1, 256, 0, stream>>>(partial, out, scale);
}